// Round 6
// baseline (597.415 us; speedup 1.0000x reference)
//
#include <hip/hip_runtime.h>
#include <math.h>

typedef unsigned int u32;
typedef unsigned short u16;

#define T_ 16
#define B_ 32
#define S_ 256
#define H_ 256
#define E_ 300
#define V_ 1000

__device__ __forceinline__ float fast_tanh(float x) {
    return 1.0f - 2.0f / (__expf(2.0f * x) + 1.0f);
}
__device__ __forceinline__ float fast_sigm(float x) {
    return 1.0f / (1.0f + __expf(-x));
}
__device__ __forceinline__ float bf2f(u16 x) { return __uint_as_float(((u32)x) << 16); }
__device__ __forceinline__ float blo(u32 u) { return __uint_as_float(u << 16); }
__device__ __forceinline__ float bhi(u32 u) { return __uint_as_float(u & 0xffff0000u); }
__device__ __forceinline__ u16 f2bf(float f) {
    u32 u = __float_as_uint(f);
    u32 r = (u + 0x7fffu + ((u >> 16) & 1u)) >> 16;
    return (u16)r;
}

// ---------------------------------------------------------------------------
// Generic GEMM: C[M,N] = A[M,K](fp32, optional row-gather) @ Bw[N,K]^T + bias
// Tile 64x64, BK=32, 256 threads, 4x4 outputs/thread. M multiple of 64.
// ---------------------------------------------------------------------------
__global__ __launch_bounds__(256)
void gemm_bt(const float* __restrict__ A, const int* __restrict__ gidx, int lda,
             const float* __restrict__ Bw, const float* __restrict__ bias,
             float* __restrict__ C, int N, int K, int ldc)
{
    __shared__ float As[32][64];
    __shared__ float Bs[32][64];
    const int tid = threadIdx.x;
    const int bm = blockIdx.y * 64;
    const int bn = blockIdx.x * 64;
    const int ty = tid >> 4, tx = tid & 15;
    const int lr = tid >> 2;            // 0..63 tile row
    const int lk = (tid & 3) * 8;       // k offset within BK

    int am = bm + lr;
    int arow = gidx ? gidx[am] : am;
    const float* Ap = A + (size_t)arow * lda;
    int bnr = bn + lr;
    const float* Bp = (bnr < N) ? (Bw + (size_t)bnr * K) : nullptr;

    float acc[4][4] = {};

    for (int k0 = 0; k0 < K; k0 += 32) {
        int kb = k0 + lk;
        float av[8];
        if (kb + 8 <= K) {
            float4 p0 = *(const float4*)(Ap + kb);
            float4 p1 = *(const float4*)(Ap + kb + 4);
            av[0]=p0.x; av[1]=p0.y; av[2]=p0.z; av[3]=p0.w;
            av[4]=p1.x; av[5]=p1.y; av[6]=p1.z; av[7]=p1.w;
        } else {
            #pragma unroll
            for (int j = 0; j < 8; j++) av[j] = (kb + j < K) ? Ap[kb + j] : 0.0f;
        }
        #pragma unroll
        for (int j = 0; j < 8; j++) As[lk + j][lr] = av[j];
        if (Bp && kb + 8 <= K) {
            float4 p0 = *(const float4*)(Bp + kb);
            float4 p1 = *(const float4*)(Bp + kb + 4);
            av[0]=p0.x; av[1]=p0.y; av[2]=p0.z; av[3]=p0.w;
            av[4]=p1.x; av[5]=p1.y; av[6]=p1.z; av[7]=p1.w;
        } else if (Bp) {
            #pragma unroll
            for (int j = 0; j < 8; j++) av[j] = (kb + j < K) ? Bp[kb + j] : 0.0f;
        } else {
            #pragma unroll
            for (int j = 0; j < 8; j++) av[j] = 0.0f;
        }
        #pragma unroll
        for (int j = 0; j < 8; j++) Bs[lk + j][lr] = av[j];
        __syncthreads();
        #pragma unroll
        for (int kk = 0; kk < 32; kk++) {
            float4 a = *(const float4*)&As[kk][ty * 4];
            float4 b = *(const float4*)&Bs[kk][tx * 4];
            acc[0][0] += a.x*b.x; acc[0][1] += a.x*b.y; acc[0][2] += a.x*b.z; acc[0][3] += a.x*b.w;
            acc[1][0] += a.y*b.x; acc[1][1] += a.y*b.y; acc[1][2] += a.y*b.z; acc[1][3] += a.y*b.w;
            acc[2][0] += a.z*b.x; acc[2][1] += a.z*b.y; acc[2][2] += a.z*b.z; acc[2][3] += a.z*b.w;
            acc[3][0] += a.w*b.x; acc[3][1] += a.w*b.y; acc[3][2] += a.w*b.z; acc[3][3] += a.w*b.w;
        }
        __syncthreads();
    }
    #pragma unroll
    for (int i = 0; i < 4; i++) {
        int m = bm + ty * 4 + i;
        #pragma unroll
        for (int j = 0; j < 4; j++) {
            int n = bn + tx * 4 + j;
            if (n < N) C[(size_t)m * ldc + n] = acc[i][j] + bias[n];
        }
    }
}

// ---------------------------------------------------------------------------
// One-time transpose: Wt[k][r] = bf16(W_hh[r][k]).  idx = k*1024 + r.
// ---------------------------------------------------------------------------
__global__ __launch_bounds__(256)
void transpose_whh(const float* __restrict__ Whh, u16* __restrict__ Wt)
{
    int idx = blockIdx.x * 256 + threadIdx.x;      // 0 .. 262143
    int k = idx >> 10;
    int r = idx & 1023;
    Wt[idx] = f2bf(Whh[(size_t)r * 256 + k]);
}

// ---------------------------------------------------------------------------
// LSTM scan v4: 32 blocks (one per batch), 1024 threads.
// Thread = (kg, rq): kg = tid>>7 owns k-slice [kg*32, kg*32+32);
//                    rq = tid&127 owns 8 consecutive r-columns r0 = rq*8.
// Per k: ONE uint4 load (8 bf16, 16 B/lane — coalescing sweet spot) instead of
// round-5's 2-byte scalar loads (the issue-rate killer). Partials reduced via
// zp[8][1024] in LDS, then gates. No cross-block comm.
// ---------------------------------------------------------------------------
__global__ __launch_bounds__(1024)
void lstm_scan4(const float* __restrict__ xproj,   // [T,B,1024]
                const u16*   __restrict__ Wt,      // [256,1024] bf16
                const float* __restrict__ bhh,     // [1024]
                const float* __restrict__ h0, const float* __restrict__ c0,
                float* __restrict__ combined,      // [T,B,512] second half
                float* __restrict__ hT, float* __restrict__ cT)
{
    const int b   = blockIdx.x;
    const int tid = threadIdx.x;
    const int kg  = tid >> 7;           // 0..7
    const int rq  = tid & 127;          // r-octet
    const int r0  = rq * 8;
    __shared__ float hs[256], cs[256];
    __shared__ float zp[8][1024];

    if (tid < 256) {
        hs[tid] = h0[b * 256 + tid];
        cs[tid] = c0[b * 256 + tid];
    }
    const float bh = bhh[tid];
    const u16* wbase = Wt + (size_t)(kg * 32) * 1024 + r0;
    __syncthreads();

    for (int t = 0; t < T_; t++) {
        float acc[8] = {};
        #pragma unroll
        for (int kk = 0; kk < 32; kk += 4) {
            float4 h4 = *(const float4*)&hs[kg * 32 + kk];   // LDS broadcast
            uint4 wA = *(const uint4*)(wbase + (size_t)(kk + 0) * 1024);
            uint4 wB = *(const uint4*)(wbase + (size_t)(kk + 1) * 1024);
            uint4 wC = *(const uint4*)(wbase + (size_t)(kk + 2) * 1024);
            uint4 wD = *(const uint4*)(wbase + (size_t)(kk + 3) * 1024);
            acc[0] += blo(wA.x)*h4.x; acc[1] += bhi(wA.x)*h4.x;
            acc[2] += blo(wA.y)*h4.x; acc[3] += bhi(wA.y)*h4.x;
            acc[4] += blo(wA.z)*h4.x; acc[5] += bhi(wA.z)*h4.x;
            acc[6] += blo(wA.w)*h4.x; acc[7] += bhi(wA.w)*h4.x;
            acc[0] += blo(wB.x)*h4.y; acc[1] += bhi(wB.x)*h4.y;
            acc[2] += blo(wB.y)*h4.y; acc[3] += bhi(wB.y)*h4.y;
            acc[4] += blo(wB.z)*h4.y; acc[5] += bhi(wB.z)*h4.y;
            acc[6] += blo(wB.w)*h4.y; acc[7] += bhi(wB.w)*h4.y;
            acc[0] += blo(wC.x)*h4.z; acc[1] += bhi(wC.x)*h4.z;
            acc[2] += blo(wC.y)*h4.z; acc[3] += bhi(wC.y)*h4.z;
            acc[4] += blo(wC.z)*h4.z; acc[5] += bhi(wC.z)*h4.z;
            acc[6] += blo(wC.w)*h4.z; acc[7] += bhi(wC.w)*h4.z;
            acc[0] += blo(wD.x)*h4.w; acc[1] += bhi(wD.x)*h4.w;
            acc[2] += blo(wD.y)*h4.w; acc[3] += bhi(wD.y)*h4.w;
            acc[4] += blo(wD.z)*h4.w; acc[5] += bhi(wD.z)*h4.w;
            acc[6] += blo(wD.w)*h4.w; acc[7] += bhi(wD.w)*h4.w;
        }
        // store partials (two b128 writes)
        *(float4*)&zp[kg][r0]     = make_float4(acc[0], acc[1], acc[2], acc[3]);
        *(float4*)&zp[kg][r0 + 4] = make_float4(acc[4], acc[5], acc[6], acc[7]);
        __syncthreads();

        // z[tid] = xproj + bias + sum of 8 partials
        float z = xproj[((size_t)t * B_ + b) * 1024 + tid] + bh;
        #pragma unroll
        for (int g = 0; g < 8; g++) z += zp[g][tid];
        zp[0][tid] = z;
        __syncthreads();

        if (tid < 256) {
            float ig = fast_sigm(zp[0][tid]);
            float fg = fast_sigm(zp[0][256 + tid]);
            float gg = fast_tanh(zp[0][512 + tid]);
            float og = fast_sigm(zp[0][768 + tid]);
            float c = fg * cs[tid] + ig * gg;
            float h = og * fast_tanh(c);
            cs[tid] = c;
            hs[tid] = h;
            combined[((size_t)t * B_ + b) * 512 + 256 + tid] = h;
            if (t == T_ - 1) {
                hT[b * 256 + tid] = h;
                cT[b * 256 + tid] = c;
            }
        }
        __syncthreads();
    }
}

// ---------------------------------------------------------------------------
// Fused attention: scores (tanh additive) + masked softmax + context.
// Block per (b,t), 256 threads.
// ---------------------------------------------------------------------------
__global__ __launch_bounds__(256)
void attn_fused(const float* __restrict__ enct,   // [S,B,H]
                const float* __restrict__ dect,   // [T,B,H]
                const float* __restrict__ enc_raw,// [S,B,H]
                const float* __restrict__ wa, const float* __restrict__ ba,
                const int* __restrict__ lens,
                float* __restrict__ ctx_out,      // [B,T,H] (d_out)
                float* __restrict__ combined)     // [T,B,512] first half
{
    const int bid = blockIdx.x;
    const int b = bid >> 4;
    const int t = bid & 15;
    const int tid = threadIdx.x;
    __shared__ float ds[256], was[256], sc[256];
    __shared__ float red[8];

    ds[tid]  = dect[((size_t)t * B_ + b) * 256 + tid];
    was[tid] = wa[tid];
    const int len = lens[b];
    const float bav = ba[0];
    __syncthreads();

    const int wv = tid >> 6, lane = tid & 63;
    for (int s = wv; s < len; s += 4) {
        const float* er = enct + ((size_t)s * B_ + b) * 256;
        float sum = 0.0f;
        #pragma unroll
        for (int j = 0; j < 4; j++) {
            int h = lane + 64 * j;
            sum += fast_tanh(er[h] + ds[h]) * was[h];
        }
        #pragma unroll
        for (int off = 32; off >= 1; off >>= 1) sum += __shfl_xor(sum, off, 64);
        if (lane == 0) sc[s] = sum + bav;
    }
    __syncthreads();

    float x = (tid < len) ? sc[tid] : -INFINITY;
    float m = x;
    #pragma unroll
    for (int off = 32; off >= 1; off >>= 1) m = fmaxf(m, __shfl_xor(m, off, 64));
    if (lane == 0) red[wv] = m;
    __syncthreads();
    m = fmaxf(fmaxf(red[0], red[1]), fmaxf(red[2], red[3]));
    float e = __expf(x - m);
    float ssum = e;
    #pragma unroll
    for (int off = 32; off >= 1; off >>= 1) ssum += __shfl_xor(ssum, off, 64);
    if (lane == 0) red[4 + wv] = ssum;
    __syncthreads();
    ssum = red[4] + red[5] + red[6] + red[7];
    __syncthreads();
    sc[tid] = e / ssum;
    __syncthreads();

    float acc = 0.0f;
    const float* eb = enc_raw + (size_t)b * 256 + tid;
    for (int s = 0; s < len; s++) acc += sc[s] * eb[(size_t)s * (B_ * H_)];
    ctx_out[((size_t)b * T_ + t) * 256 + tid] = acc;
    combined[((size_t)t * B_ + b) * 512 + tid] = acc;
}

// ---------------------------------------------------------------------------
// Vocab softmax: block per (t,b) row, 256 threads x 4 elems (V=1000).
// ---------------------------------------------------------------------------
__global__ __launch_bounds__(256)
void vocab_softmax(const float* __restrict__ logits, float* __restrict__ probs)
{
    const int r = blockIdx.x;
    const int tid = threadIdx.x;
    const int wv = tid >> 6, lane = tid & 63;
    __shared__ float red[8];
    const float* row = logits + (size_t)r * V_;
    float v[4];
    float mx = -INFINITY;
    #pragma unroll
    for (int j = 0; j < 4; j++) {
        int idx = tid + 256 * j;
        v[j] = (idx < V_) ? row[idx] : -INFINITY;
        mx = fmaxf(mx, v[j]);
    }
    #pragma unroll
    for (int off = 32; off >= 1; off >>= 1) mx = fmaxf(mx, __shfl_xor(mx, off, 64));
    if (lane == 0) red[wv] = mx;
    __syncthreads();
    mx = fmaxf(fmaxf(red[0], red[1]), fmaxf(red[2], red[3]));
    float s = 0.0f;
    #pragma unroll
    for (int j = 0; j < 4; j++) {
        v[j] = __expf(v[j] - mx);
        s += v[j];
    }
    #pragma unroll
    for (int off = 32; off >= 1; off >>= 1) s += __shfl_xor(s, off, 64);
    if (lane == 0) red[4 + wv] = s;
    __syncthreads();
    s = red[4] + red[5] + red[6] + red[7];
    float inv = 1.0f / s;
    #pragma unroll
    for (int j = 0; j < 4; j++) {
        int idx = tid + 256 * j;
        if (idx < V_) probs[(size_t)r * V_ + idx] = v[j] * inv;
    }
}

extern "C" void kernel_launch(void* const* d_in, const int* in_sizes, int n_in,
                              void* d_out, int out_size, void* d_ws, size_t ws_size,
                              hipStream_t stream) {
    const int*   tv       = (const int*)d_in[0];     // [T,B]
    const float* h0       = (const float*)d_in[1];   // [1,B,H]
    const float* c0       = (const float*)d_in[2];
    const float* enc_raw  = (const float*)d_in[3];   // [S,B,H]
    const int*   lens     = (const int*)d_in[4];     // [B]
    const float* emb      = (const float*)d_in[5];   // [V,E]
    const float* W_ih     = (const float*)d_in[6];   // [4H,E]
    const float* W_hh     = (const float*)d_in[7];   // [4H,H]
    const float* b_ih     = (const float*)d_in[8];
    const float* b_hh     = (const float*)d_in[9];
    const float* We       = (const float*)d_in[10];  // [H,H]
    const float* be       = (const float*)d_in[11];
    const float* Wd       = (const float*)d_in[12];
    const float* bd       = (const float*)d_in[13];
    const float* wa       = (const float*)d_in[14];  // [H]
    const float* ba       = (const float*)d_in[15];  // [1]
    const float* W_out    = (const float*)d_in[16];  // [V,2H]
    const float* b_out    = (const float*)d_in[17];

    // workspace layout (fp32 words; 14.6 MB total)
    float* ws       = (float*)d_ws;
    float* enct     = ws;                       // [S*B,256]   2,097,152
    float* xproj    = ws + 2097152;             // [T*B,1024]    524,288
    float* dect     = ws + 2621440;             // [T*B,256]     131,072
    float* logits   = ws + 2752512;             // [T*B,1000]    512,000
    float* combined = ws + 3264512;             // [T*B,512]     262,144
    u16*   Wt       = (u16*)(ws + 3526656);     // [256,1024] bf16 = 262,144 u16

    // d_out layout (fp32): probs [T,B,V], hT [1,B,H], cT [1,B,H], ctx [B,T,H]
    float* out      = (float*)d_out;
    float* probs    = out;
    float* hT       = out + 512000;
    float* cT       = out + 520192;
    float* ctx_out  = out + 528384;

    // 0) transpose W_hh -> Wt (bf16, [k][r])
    transpose_whh<<<1024, 256, 0, stream>>>(W_hh, Wt);
    // 1) x_proj = gather(emb, tv) @ W_ih^T + b_ih  -> [T*B, 1024]
    {
        dim3 grid(1024 / 64, 512 / 64);
        gemm_bt<<<grid, 256, 0, stream>>>(emb, tv, E_, W_ih, b_ih, xproj, 1024, E_, 1024);
    }
    // 2) enc_t = enc_raw @ We^T + be  -> [S*B, 256]
    {
        dim3 grid(256 / 64, 8192 / 64);
        gemm_bt<<<grid, 256, 0, stream>>>(enc_raw, nullptr, H_, We, be, enct, 256, H_, 256);
    }
    // 3) LSTM scan v4 (32 blocks, uint4 W loads, LDS k-split reduction)
    lstm_scan4<<<32, 1024, 0, stream>>>(xproj, Wt, b_hh, h0, c0, combined, hT, cT);
    // 4) dec_t = output @ Wd^T + bd  -> [T*B, 256]
    {
        dim3 grid(256 / 64, 512 / 64);
        gemm_bt<<<grid, 256, 0, stream>>>(combined + 256, nullptr, 512, Wd, bd, dect, 256, H_, 256);
    }
    // 5) fused attention -> context
    attn_fused<<<512, 256, 0, stream>>>(enct, dect, enc_raw, wa, ba, lens, ctx_out, combined);
    // 6) logits = combined @ W_out^T + b_out -> [T*B, 1000]
    {
        dim3 grid((1000 + 63) / 64, 512 / 64);
        gemm_bt<<<grid, 256, 0, stream>>>(combined, nullptr, 512, W_out, b_out, logits, V_, 512, V_);
    }
    // 7) vocab softmax -> probs
    vocab_softmax<<<512, 256, 0, stream>>>(logits, probs);
}

// Round 7
// 563.044 us; speedup vs baseline: 1.0610x; 1.0610x over previous
//
#include <hip/hip_runtime.h>
#include <math.h>

typedef unsigned int u32;
typedef unsigned short u16;

#define T_ 16
#define B_ 32
#define S_ 256
#define H_ 256
#define E_ 300
#define V_ 1000

__device__ __forceinline__ float fast_tanh(float x) {
    return 1.0f - 2.0f / (__expf(2.0f * x) + 1.0f);
}
__device__ __forceinline__ float fast_sigm(float x) {
    return 1.0f / (1.0f + __expf(-x));
}
__device__ __forceinline__ float bf2f(u16 x) { return __uint_as_float(((u32)x) << 16); }
__device__ __forceinline__ float blo(u32 u) { return __uint_as_float(u << 16); }
__device__ __forceinline__ float bhi(u32 u) { return __uint_as_float(u & 0xffff0000u); }
__device__ __forceinline__ u16 f2bf(float f) {
    u32 u = __float_as_uint(f);
    u32 r = (u + 0x7fffu + ((u >> 16) & 1u)) >> 16;
    return (u16)r;
}

// ---------------------------------------------------------------------------
// Generic GEMM: C[M,N] = A[M,K](fp32, optional row-gather) @ Bw[N,K]^T + bias
// Tile 64x64, BK=32, 256 threads, 4x4 outputs/thread. M multiple of 64.
// ---------------------------------------------------------------------------
__global__ __launch_bounds__(256)
void gemm_bt(const float* __restrict__ A, const int* __restrict__ gidx, int lda,
             const float* __restrict__ Bw, const float* __restrict__ bias,
             float* __restrict__ C, int N, int K, int ldc)
{
    __shared__ float As[32][64];
    __shared__ float Bs[32][64];
    const int tid = threadIdx.x;
    const int bm = blockIdx.y * 64;
    const int bn = blockIdx.x * 64;
    const int ty = tid >> 4, tx = tid & 15;
    const int lr = tid >> 2;            // 0..63 tile row
    const int lk = (tid & 3) * 8;       // k offset within BK

    int am = bm + lr;
    int arow = gidx ? gidx[am] : am;
    const float* Ap = A + (size_t)arow * lda;
    int bnr = bn + lr;
    const float* Bp = (bnr < N) ? (Bw + (size_t)bnr * K) : nullptr;

    float acc[4][4] = {};

    for (int k0 = 0; k0 < K; k0 += 32) {
        int kb = k0 + lk;
        float av[8];
        if (kb + 8 <= K) {
            float4 p0 = *(const float4*)(Ap + kb);
            float4 p1 = *(const float4*)(Ap + kb + 4);
            av[0]=p0.x; av[1]=p0.y; av[2]=p0.z; av[3]=p0.w;
            av[4]=p1.x; av[5]=p1.y; av[6]=p1.z; av[7]=p1.w;
        } else {
            #pragma unroll
            for (int j = 0; j < 8; j++) av[j] = (kb + j < K) ? Ap[kb + j] : 0.0f;
        }
        #pragma unroll
        for (int j = 0; j < 8; j++) As[lk + j][lr] = av[j];
        if (Bp && kb + 8 <= K) {
            float4 p0 = *(const float4*)(Bp + kb);
            float4 p1 = *(const float4*)(Bp + kb + 4);
            av[0]=p0.x; av[1]=p0.y; av[2]=p0.z; av[3]=p0.w;
            av[4]=p1.x; av[5]=p1.y; av[6]=p1.z; av[7]=p1.w;
        } else if (Bp) {
            #pragma unroll
            for (int j = 0; j < 8; j++) av[j] = (kb + j < K) ? Bp[kb + j] : 0.0f;
        } else {
            #pragma unroll
            for (int j = 0; j < 8; j++) av[j] = 0.0f;
        }
        #pragma unroll
        for (int j = 0; j < 8; j++) Bs[lk + j][lr] = av[j];
        __syncthreads();
        #pragma unroll
        for (int kk = 0; kk < 32; kk++) {
            float4 a = *(const float4*)&As[kk][ty * 4];
            float4 b = *(const float4*)&Bs[kk][tx * 4];
            acc[0][0] += a.x*b.x; acc[0][1] += a.x*b.y; acc[0][2] += a.x*b.z; acc[0][3] += a.x*b.w;
            acc[1][0] += a.y*b.x; acc[1][1] += a.y*b.y; acc[1][2] += a.y*b.z; acc[1][3] += a.y*b.w;
            acc[2][0] += a.z*b.x; acc[2][1] += a.z*b.y; acc[2][2] += a.z*b.z; acc[2][3] += a.z*b.w;
            acc[3][0] += a.w*b.x; acc[3][1] += a.w*b.y; acc[3][2] += a.w*b.z; acc[3][3] += a.w*b.w;
        }
        __syncthreads();
    }
    #pragma unroll
    for (int i = 0; i < 4; i++) {
        int m = bm + ty * 4 + i;
        #pragma unroll
        for (int j = 0; j < 4; j++) {
            int n = bn + tx * 4 + j;
            if (n < N) C[(size_t)m * ldc + n] = acc[i][j] + bias[n];
        }
    }
}

// ---------------------------------------------------------------------------
// One-time transpose: Wt[k][r] = bf16(W_hh[r][k]).  idx = k*1024 + r.
// ---------------------------------------------------------------------------
__global__ __launch_bounds__(256)
void transpose_whh(const float* __restrict__ Whh, u16* __restrict__ Wt)
{
    int idx = blockIdx.x * 256 + threadIdx.x;      // 0 .. 262143
    int k = idx >> 10;
    int r = idx & 1023;
    Wt[idx] = f2bf(Whh[(size_t)r * 256 + k]);
}

// ---------------------------------------------------------------------------
// LSTM scan v5: 32 blocks (one per batch), 1024 threads.
// Thread = (kg, rq): kg = tid>>8 (0..3) owns k-slice [kg*64, kg*64+64);
//                    rq = tid&255 owns 4 consecutive r-columns r0 = rq*4.
// Per k: ONE uint2 load (4 bf16, 8 B/lane, 512 B/wave contiguous).
// acc[4] + ~8 load temps keeps VGPR ~30 — well under the 128 ceiling from
// __launch_bounds__(1024,4). (Round-6 lesson: plain (1024) let the compiler
// cap at 64 VGPR -> scratch spill -> 22 MB HBM writes -> 2.4x regression.)
// Partials via zp[4][1024] LDS (16 KB); no cross-block comm.
// ---------------------------------------------------------------------------
__global__ __launch_bounds__(1024, 4)
void lstm_scan5(const float* __restrict__ xproj,   // [T,B,1024]
                const u16*   __restrict__ Wt,      // [256,1024] bf16
                const float* __restrict__ bhh,     // [1024]
                const float* __restrict__ h0, const float* __restrict__ c0,
                float* __restrict__ combined,      // [T,B,512] second half
                float* __restrict__ hT, float* __restrict__ cT)
{
    const int b   = blockIdx.x;
    const int tid = threadIdx.x;
    const int kg  = tid >> 8;           // 0..3
    const int rq  = tid & 255;          // r-quad
    const int r0  = rq * 4;
    __shared__ float hs[256], cs[256];
    __shared__ float zp[4][1024];

    if (tid < 256) {
        hs[tid] = h0[b * 256 + tid];
        cs[tid] = c0[b * 256 + tid];
    }
    const float bh = bhh[tid];
    const u16* wbase = Wt + (size_t)(kg * 64) * 1024 + r0;
    __syncthreads();

    for (int t = 0; t < T_; t++) {
        float a0 = 0.f, a1 = 0.f, a2 = 0.f, a3 = 0.f;
        #pragma unroll
        for (int kk = 0; kk < 64; kk += 4) {
            float4 h4 = *(const float4*)&hs[kg * 64 + kk];   // LDS broadcast
            uint2 wA = *(const uint2*)(wbase + (size_t)(kk + 0) * 1024);
            uint2 wB = *(const uint2*)(wbase + (size_t)(kk + 1) * 1024);
            uint2 wC = *(const uint2*)(wbase + (size_t)(kk + 2) * 1024);
            uint2 wD = *(const uint2*)(wbase + (size_t)(kk + 3) * 1024);
            a0 += blo(wA.x)*h4.x; a1 += bhi(wA.x)*h4.x;
            a2 += blo(wA.y)*h4.x; a3 += bhi(wA.y)*h4.x;
            a0 += blo(wB.x)*h4.y; a1 += bhi(wB.x)*h4.y;
            a2 += blo(wB.y)*h4.y; a3 += bhi(wB.y)*h4.y;
            a0 += blo(wC.x)*h4.z; a1 += bhi(wC.x)*h4.z;
            a2 += blo(wC.y)*h4.z; a3 += bhi(wC.y)*h4.z;
            a0 += blo(wD.x)*h4.w; a1 += bhi(wD.x)*h4.w;
            a2 += blo(wD.y)*h4.w; a3 += bhi(wD.y)*h4.w;
        }
        *(float4*)&zp[kg][r0] = make_float4(a0, a1, a2, a3);
        __syncthreads();

        // z[tid] = xproj + bias + sum of 4 partials
        float z = xproj[((size_t)t * B_ + b) * 1024 + tid] + bh
                + zp[0][tid] + zp[1][tid] + zp[2][tid] + zp[3][tid];
        __syncthreads();
        zp[0][tid] = z;
        __syncthreads();

        if (tid < 256) {
            float ig = fast_sigm(zp[0][tid]);
            float fg = fast_sigm(zp[0][256 + tid]);
            float gg = fast_tanh(zp[0][512 + tid]);
            float og = fast_sigm(zp[0][768 + tid]);
            float c = fg * cs[tid] + ig * gg;
            float h = og * fast_tanh(c);
            cs[tid] = c;
            hs[tid] = h;
            combined[((size_t)t * B_ + b) * 512 + 256 + tid] = h;
            if (t == T_ - 1) {
                hT[b * 256 + tid] = h;
                cT[b * 256 + tid] = c;
            }
        }
        __syncthreads();
    }
}

// ---------------------------------------------------------------------------
// Fused attention: scores (tanh additive) + masked softmax + context.
// Block per (b,t), 256 threads.
// ---------------------------------------------------------------------------
__global__ __launch_bounds__(256)
void attn_fused(const float* __restrict__ enct,   // [S,B,H]
                const float* __restrict__ dect,   // [T,B,H]
                const float* __restrict__ enc_raw,// [S,B,H]
                const float* __restrict__ wa, const float* __restrict__ ba,
                const int* __restrict__ lens,
                float* __restrict__ ctx_out,      // [B,T,H] (d_out)
                float* __restrict__ combined)     // [T,B,512] first half
{
    const int bid = blockIdx.x;
    const int b = bid >> 4;
    const int t = bid & 15;
    const int tid = threadIdx.x;
    __shared__ float ds[256], was[256], sc[256];
    __shared__ float red[8];

    ds[tid]  = dect[((size_t)t * B_ + b) * 256 + tid];
    was[tid] = wa[tid];
    const int len = lens[b];
    const float bav = ba[0];
    __syncthreads();

    const int wv = tid >> 6, lane = tid & 63;
    for (int s = wv; s < len; s += 4) {
        const float* er = enct + ((size_t)s * B_ + b) * 256;
        float sum = 0.0f;
        #pragma unroll
        for (int j = 0; j < 4; j++) {
            int h = lane + 64 * j;
            sum += fast_tanh(er[h] + ds[h]) * was[h];
        }
        #pragma unroll
        for (int off = 32; off >= 1; off >>= 1) sum += __shfl_xor(sum, off, 64);
        if (lane == 0) sc[s] = sum + bav;
    }
    __syncthreads();

    float x = (tid < len) ? sc[tid] : -INFINITY;
    float m = x;
    #pragma unroll
    for (int off = 32; off >= 1; off >>= 1) m = fmaxf(m, __shfl_xor(m, off, 64));
    if (lane == 0) red[wv] = m;
    __syncthreads();
    m = fmaxf(fmaxf(red[0], red[1]), fmaxf(red[2], red[3]));
    float e = __expf(x - m);
    float ssum = e;
    #pragma unroll
    for (int off = 32; off >= 1; off >>= 1) ssum += __shfl_xor(ssum, off, 64);
    if (lane == 0) red[4 + wv] = ssum;
    __syncthreads();
    ssum = red[4] + red[5] + red[6] + red[7];
    __syncthreads();
    sc[tid] = e / ssum;
    __syncthreads();

    float acc = 0.0f;
    const float* eb = enc_raw + (size_t)b * 256 + tid;
    for (int s = 0; s < len; s++) acc += sc[s] * eb[(size_t)s * (B_ * H_)];
    ctx_out[((size_t)b * T_ + t) * 256 + tid] = acc;
    combined[((size_t)t * B_ + b) * 512 + tid] = acc;
}

// ---------------------------------------------------------------------------
// Vocab softmax: block per (t,b) row, 256 threads x 4 elems (V=1000).
// ---------------------------------------------------------------------------
__global__ __launch_bounds__(256)
void vocab_softmax(const float* __restrict__ logits, float* __restrict__ probs)
{
    const int r = blockIdx.x;
    const int tid = threadIdx.x;
    const int wv = tid >> 6, lane = tid & 63;
    __shared__ float red[8];
    const float* row = logits + (size_t)r * V_;
    float v[4];
    float mx = -INFINITY;
    #pragma unroll
    for (int j = 0; j < 4; j++) {
        int idx = tid + 256 * j;
        v[j] = (idx < V_) ? row[idx] : -INFINITY;
        mx = fmaxf(mx, v[j]);
    }
    #pragma unroll
    for (int off = 32; off >= 1; off >>= 1) mx = fmaxf(mx, __shfl_xor(mx, off, 64));
    if (lane == 0) red[wv] = mx;
    __syncthreads();
    mx = fmaxf(fmaxf(red[0], red[1]), fmaxf(red[2], red[3]));
    float s = 0.0f;
    #pragma unroll
    for (int j = 0; j < 4; j++) {
        v[j] = __expf(v[j] - mx);
        s += v[j];
    }
    #pragma unroll
    for (int off = 32; off >= 1; off >>= 1) s += __shfl_xor(s, off, 64);
    if (lane == 0) red[4 + wv] = s;
    __syncthreads();
    s = red[4] + red[5] + red[6] + red[7];
    float inv = 1.0f / s;
    #pragma unroll
    for (int j = 0; j < 4; j++) {
        int idx = tid + 256 * j;
        if (idx < V_) probs[(size_t)r * V_ + idx] = v[j] * inv;
    }
}

extern "C" void kernel_launch(void* const* d_in, const int* in_sizes, int n_in,
                              void* d_out, int out_size, void* d_ws, size_t ws_size,
                              hipStream_t stream) {
    const int*   tv       = (const int*)d_in[0];     // [T,B]
    const float* h0       = (const float*)d_in[1];   // [1,B,H]
    const float* c0       = (const float*)d_in[2];
    const float* enc_raw  = (const float*)d_in[3];   // [S,B,H]
    const int*   lens     = (const int*)d_in[4];     // [B]
    const float* emb      = (const float*)d_in[5];   // [V,E]
    const float* W_ih     = (const float*)d_in[6];   // [4H,E]
    const float* W_hh     = (const float*)d_in[7];   // [4H,H]
    const float* b_ih     = (const float*)d_in[8];
    const float* b_hh     = (const float*)d_in[9];
    const float* We       = (const float*)d_in[10];  // [H,H]
    const float* be       = (const float*)d_in[11];
    const float* Wd       = (const float*)d_in[12];
    const float* bd       = (const float*)d_in[13];
    const float* wa       = (const float*)d_in[14];  // [H]
    const float* ba       = (const float*)d_in[15];  // [1]
    const float* W_out    = (const float*)d_in[16];  // [V,2H]
    const float* b_out    = (const float*)d_in[17];

    // workspace layout (fp32 words; 14.6 MB total)
    float* ws       = (float*)d_ws;
    float* enct     = ws;                       // [S*B,256]   2,097,152
    float* xproj    = ws + 2097152;             // [T*B,1024]    524,288
    float* dect     = ws + 2621440;             // [T*B,256]     131,072
    float* logits   = ws + 2752512;             // [T*B,1000]    512,000
    float* combined = ws + 3264512;             // [T*B,512]     262,144
    u16*   Wt       = (u16*)(ws + 3526656);     // [256,1024] bf16 = 262,144 u16

    // d_out layout (fp32): probs [T,B,V], hT [1,B,H], cT [1,B,H], ctx [B,T,H]
    float* out      = (float*)d_out;
    float* probs    = out;
    float* hT       = out + 512000;
    float* cT       = out + 520192;
    float* ctx_out  = out + 528384;

    // 0) transpose W_hh -> Wt (bf16, [k][r])
    transpose_whh<<<1024, 256, 0, stream>>>(W_hh, Wt);
    // 1) x_proj = gather(emb, tv) @ W_ih^T + b_ih  -> [T*B, 1024]
    {
        dim3 grid(1024 / 64, 512 / 64);
        gemm_bt<<<grid, 256, 0, stream>>>(emb, tv, E_, W_ih, b_ih, xproj, 1024, E_, 1024);
    }
    // 2) enc_t = enc_raw @ We^T + be  -> [S*B, 256]
    {
        dim3 grid(256 / 64, 8192 / 64);
        gemm_bt<<<grid, 256, 0, stream>>>(enc_raw, nullptr, H_, We, be, enct, 256, H_, 256);
    }
    // 3) LSTM scan v5 (32 blocks, uint2 W loads, acc[4], no spill)
    lstm_scan5<<<32, 1024, 0, stream>>>(xproj, Wt, b_hh, h0, c0, combined, hT, cT);
    // 4) dec_t = output @ Wd^T + bd  -> [T*B, 256]
    {
        dim3 grid(256 / 64, 512 / 64);
        gemm_bt<<<grid, 256, 0, stream>>>(combined + 256, nullptr, 512, Wd, bd, dect, 256, H_, 256);
    }
    // 5) fused attention -> context
    attn_fused<<<512, 256, 0, stream>>>(enct, dect, enc_raw, wa, ba, lens, ctx_out, combined);
    // 6) logits = combined @ W_out^T + b_out -> [T*B, 1000]
    {
        dim3 grid((1000 + 63) / 64, 512 / 64);
        gemm_bt<<<grid, 256, 0, stream>>>(combined, nullptr, 512, W_out, b_out, logits, V_, 512, V_);
    }
    // 7) vocab softmax -> probs
    vocab_softmax<<<512, 256, 0, stream>>>(logits, probs);
}

// Round 8
// 336.811 us; speedup vs baseline: 1.7737x; 1.6717x over previous
//
#include <hip/hip_runtime.h>
#include <math.h>

typedef unsigned int u32;
typedef unsigned short u16;

#define T_ 16
#define B_ 32
#define S_ 256
#define H_ 256
#define E_ 300
#define V_ 1000

__device__ __forceinline__ float fast_tanh(float x) {
    return 1.0f - 2.0f / (__expf(2.0f * x) + 1.0f);
}
__device__ __forceinline__ float fast_sigm(float x) {
    return 1.0f / (1.0f + __expf(-x));
}
__device__ __forceinline__ float bf2f(u16 x) { return __uint_as_float(((u32)x) << 16); }
__device__ __forceinline__ float blo(u32 u) { return __uint_as_float(u << 16); }
__device__ __forceinline__ float bhi(u32 u) { return __uint_as_float(u & 0xffff0000u); }
__device__ __forceinline__ u16 f2bf(float f) {
    u32 u = __float_as_uint(f);
    u32 r = (u + 0x7fffu + ((u >> 16) & 1u)) >> 16;
    return (u16)r;
}

// ---------------------------------------------------------------------------
// Generic GEMM: C[M,N] = A[M,K](fp32, optional row-gather) @ Bw[N,K]^T + bias
// Tile 64x64, BK=32, 256 threads, 4x4 outputs/thread. M multiple of 64.
// ---------------------------------------------------------------------------
__global__ __launch_bounds__(256)
void gemm_bt(const float* __restrict__ A, const int* __restrict__ gidx, int lda,
             const float* __restrict__ Bw, const float* __restrict__ bias,
             float* __restrict__ C, int N, int K, int ldc)
{
    __shared__ float As[32][64];
    __shared__ float Bs[32][64];
    const int tid = threadIdx.x;
    const int bm = blockIdx.y * 64;
    const int bn = blockIdx.x * 64;
    const int ty = tid >> 4, tx = tid & 15;
    const int lr = tid >> 2;            // 0..63 tile row
    const int lk = (tid & 3) * 8;       // k offset within BK

    int am = bm + lr;
    int arow = gidx ? gidx[am] : am;
    const float* Ap = A + (size_t)arow * lda;
    int bnr = bn + lr;
    const float* Bp = (bnr < N) ? (Bw + (size_t)bnr * K) : nullptr;

    float acc[4][4] = {};

    for (int k0 = 0; k0 < K; k0 += 32) {
        int kb = k0 + lk;
        float av[8];
        if (kb + 8 <= K) {
            float4 p0 = *(const float4*)(Ap + kb);
            float4 p1 = *(const float4*)(Ap + kb + 4);
            av[0]=p0.x; av[1]=p0.y; av[2]=p0.z; av[3]=p0.w;
            av[4]=p1.x; av[5]=p1.y; av[6]=p1.z; av[7]=p1.w;
        } else {
            #pragma unroll
            for (int j = 0; j < 8; j++) av[j] = (kb + j < K) ? Ap[kb + j] : 0.0f;
        }
        #pragma unroll
        for (int j = 0; j < 8; j++) As[lk + j][lr] = av[j];
        if (Bp && kb + 8 <= K) {
            float4 p0 = *(const float4*)(Bp + kb);
            float4 p1 = *(const float4*)(Bp + kb + 4);
            av[0]=p0.x; av[1]=p0.y; av[2]=p0.z; av[3]=p0.w;
            av[4]=p1.x; av[5]=p1.y; av[6]=p1.z; av[7]=p1.w;
        } else if (Bp) {
            #pragma unroll
            for (int j = 0; j < 8; j++) av[j] = (kb + j < K) ? Bp[kb + j] : 0.0f;
        } else {
            #pragma unroll
            for (int j = 0; j < 8; j++) av[j] = 0.0f;
        }
        #pragma unroll
        for (int j = 0; j < 8; j++) Bs[lk + j][lr] = av[j];
        __syncthreads();
        #pragma unroll
        for (int kk = 0; kk < 32; kk++) {
            float4 a = *(const float4*)&As[kk][ty * 4];
            float4 b = *(const float4*)&Bs[kk][tx * 4];
            acc[0][0] += a.x*b.x; acc[0][1] += a.x*b.y; acc[0][2] += a.x*b.z; acc[0][3] += a.x*b.w;
            acc[1][0] += a.y*b.x; acc[1][1] += a.y*b.y; acc[1][2] += a.y*b.z; acc[1][3] += a.y*b.w;
            acc[2][0] += a.z*b.x; acc[2][1] += a.z*b.y; acc[2][2] += a.z*b.z; acc[2][3] += a.z*b.w;
            acc[3][0] += a.w*b.x; acc[3][1] += a.w*b.y; acc[3][2] += a.w*b.z; acc[3][3] += a.w*b.w;
        }
        __syncthreads();
    }
    #pragma unroll
    for (int i = 0; i < 4; i++) {
        int m = bm + ty * 4 + i;
        #pragma unroll
        for (int j = 0; j < 4; j++) {
            int n = bn + tx * 4 + j;
            if (n < N) C[(size_t)m * ldc + n] = acc[i][j] + bias[n];
        }
    }
}

// ---------------------------------------------------------------------------
// One-time transpose: Wt[k][r] = bf16(W_hh[r][k]).  idx = k*1024 + r.
// ---------------------------------------------------------------------------
__global__ __launch_bounds__(256)
void transpose_whh(const float* __restrict__ Whh, u16* __restrict__ Wt)
{
    int idx = blockIdx.x * 256 + threadIdx.x;      // 0 .. 262143
    int k = idx >> 10;
    int r = idx & 1023;
    Wt[idx] = f2bf(Whh[(size_t)r * 256 + k]);
}

// ---------------------------------------------------------------------------
// LSTM scan v6: 32 blocks (one per batch), 1024 threads.
// Thread = (kg, rq): kg = tid>>9 (0..1) owns k-slice [kg*128, kg*128+128);
//                    rq = tid&511 owns 2 consecutive r-columns r0 = rq*2.
// Per k: ONE u32 load (2 bf16, 4 B/lane, 256 B/wave contiguous). acc[2].
// Live set ~30 VGPR — cannot spill even at the 64-VGPR cap the compiler
// forces on 16-wave blocks. #pragma unroll 2 caps the VMEM cluster at 8
// in-flight loads (rounds 6/7 lesson: full unroll -> 64 clustered loads ->
// 128 VGPRs of destinations -> scratch spill -> 20+ MB HBM writes).
// ---------------------------------------------------------------------------
__global__ __launch_bounds__(1024, 4)
void lstm_scan6(const float* __restrict__ xproj,   // [T,B,1024]
                const u16*   __restrict__ Wt,      // [256,1024] bf16
                const float* __restrict__ bhh,     // [1024]
                const float* __restrict__ h0, const float* __restrict__ c0,
                float* __restrict__ combined,      // [T,B,512] second half
                float* __restrict__ hT, float* __restrict__ cT)
{
    const int b   = blockIdx.x;
    const int tid = threadIdx.x;
    const int kg  = tid >> 9;           // 0..1
    const int rq  = tid & 511;          // r-pair
    const int r0  = rq * 2;
    __shared__ float hs[256], cs[256];
    __shared__ float zp[2][1024];

    if (tid < 256) {
        hs[tid] = h0[b * 256 + tid];
        cs[tid] = c0[b * 256 + tid];
    }
    const float bh = bhh[tid];
    const u16* wbase = Wt + (size_t)(kg * 128) * 1024 + r0;
    __syncthreads();

    for (int t = 0; t < T_; t++) {
        float a0 = 0.f, a1 = 0.f;
        #pragma unroll 2
        for (int kk = 0; kk < 128; kk += 4) {
            float4 h4 = *(const float4*)&hs[kg * 128 + kk];  // LDS broadcast
            u32 w0 = *(const u32*)(wbase + (size_t)(kk + 0) * 1024);
            u32 w1 = *(const u32*)(wbase + (size_t)(kk + 1) * 1024);
            u32 w2 = *(const u32*)(wbase + (size_t)(kk + 2) * 1024);
            u32 w3 = *(const u32*)(wbase + (size_t)(kk + 3) * 1024);
            a0 += blo(w0)*h4.x; a1 += bhi(w0)*h4.x;
            a0 += blo(w1)*h4.y; a1 += bhi(w1)*h4.y;
            a0 += blo(w2)*h4.z; a1 += bhi(w2)*h4.z;
            a0 += blo(w3)*h4.w; a1 += bhi(w3)*h4.w;
        }
        *(float2*)&zp[kg][r0] = make_float2(a0, a1);
        __syncthreads();

        float z = xproj[((size_t)t * B_ + b) * 1024 + tid] + bh
                + zp[0][tid] + zp[1][tid];
        __syncthreads();
        zp[0][tid] = z;
        __syncthreads();

        if (tid < 256) {
            float ig = fast_sigm(zp[0][tid]);
            float fg = fast_sigm(zp[0][256 + tid]);
            float gg = fast_tanh(zp[0][512 + tid]);
            float og = fast_sigm(zp[0][768 + tid]);
            float c = fg * cs[tid] + ig * gg;
            float h = og * fast_tanh(c);
            cs[tid] = c;
            hs[tid] = h;
            combined[((size_t)t * B_ + b) * 512 + 256 + tid] = h;
            if (t == T_ - 1) {
                hT[b * 256 + tid] = h;
                cT[b * 256 + tid] = c;
            }
        }
        __syncthreads();
    }
}

// ---------------------------------------------------------------------------
// Fused attention: scores (tanh additive) + masked softmax + context.
// Block per (b,t), 256 threads.
// ---------------------------------------------------------------------------
__global__ __launch_bounds__(256)
void attn_fused(const float* __restrict__ enct,   // [S,B,H]
                const float* __restrict__ dect,   // [T,B,H]
                const float* __restrict__ enc_raw,// [S,B,H]
                const float* __restrict__ wa, const float* __restrict__ ba,
                const int* __restrict__ lens,
                float* __restrict__ ctx_out,      // [B,T,H] (d_out)
                float* __restrict__ combined)     // [T,B,512] first half
{
    const int bid = blockIdx.x;
    const int b = bid >> 4;
    const int t = bid & 15;
    const int tid = threadIdx.x;
    __shared__ float ds[256], was[256], sc[256];
    __shared__ float red[8];

    ds[tid]  = dect[((size_t)t * B_ + b) * 256 + tid];
    was[tid] = wa[tid];
    const int len = lens[b];
    const float bav = ba[0];
    __syncthreads();

    const int wv = tid >> 6, lane = tid & 63;
    for (int s = wv; s < len; s += 4) {
        const float* er = enct + ((size_t)s * B_ + b) * 256;
        float sum = 0.0f;
        #pragma unroll
        for (int j = 0; j < 4; j++) {
            int h = lane + 64 * j;
            sum += fast_tanh(er[h] + ds[h]) * was[h];
        }
        #pragma unroll
        for (int off = 32; off >= 1; off >>= 1) sum += __shfl_xor(sum, off, 64);
        if (lane == 0) sc[s] = sum + bav;
    }
    __syncthreads();

    float x = (tid < len) ? sc[tid] : -INFINITY;
    float m = x;
    #pragma unroll
    for (int off = 32; off >= 1; off >>= 1) m = fmaxf(m, __shfl_xor(m, off, 64));
    if (lane == 0) red[wv] = m;
    __syncthreads();
    m = fmaxf(fmaxf(red[0], red[1]), fmaxf(red[2], red[3]));
    float e = __expf(x - m);
    float ssum = e;
    #pragma unroll
    for (int off = 32; off >= 1; off >>= 1) ssum += __shfl_xor(ssum, off, 64);
    if (lane == 0) red[4 + wv] = ssum;
    __syncthreads();
    ssum = red[4] + red[5] + red[6] + red[7];
    __syncthreads();
    sc[tid] = e / ssum;
    __syncthreads();

    float acc = 0.0f;
    const float* eb = enc_raw + (size_t)b * 256 + tid;
    for (int s = 0; s < len; s++) acc += sc[s] * eb[(size_t)s * (B_ * H_)];
    ctx_out[((size_t)b * T_ + t) * 256 + tid] = acc;
    combined[((size_t)t * B_ + b) * 512 + tid] = acc;
}

// ---------------------------------------------------------------------------
// Vocab softmax: block per (t,b) row, 256 threads x 4 elems (V=1000).
// ---------------------------------------------------------------------------
__global__ __launch_bounds__(256)
void vocab_softmax(const float* __restrict__ logits, float* __restrict__ probs)
{
    const int r = blockIdx.x;
    const int tid = threadIdx.x;
    const int wv = tid >> 6, lane = tid & 63;
    __shared__ float red[8];
    const float* row = logits + (size_t)r * V_;
    float v[4];
    float mx = -INFINITY;
    #pragma unroll
    for (int j = 0; j < 4; j++) {
        int idx = tid + 256 * j;
        v[j] = (idx < V_) ? row[idx] : -INFINITY;
        mx = fmaxf(mx, v[j]);
    }
    #pragma unroll
    for (int off = 32; off >= 1; off >>= 1) mx = fmaxf(mx, __shfl_xor(mx, off, 64));
    if (lane == 0) red[wv] = mx;
    __syncthreads();
    mx = fmaxf(fmaxf(red[0], red[1]), fmaxf(red[2], red[3]));
    float s = 0.0f;
    #pragma unroll
    for (int j = 0; j < 4; j++) {
        v[j] = __expf(v[j] - mx);
        s += v[j];
    }
    #pragma unroll
    for (int off = 32; off >= 1; off >>= 1) s += __shfl_xor(s, off, 64);
    if (lane == 0) red[4 + wv] = s;
    __syncthreads();
    s = red[4] + red[5] + red[6] + red[7];
    float inv = 1.0f / s;
    #pragma unroll
    for (int j = 0; j < 4; j++) {
        int idx = tid + 256 * j;
        if (idx < V_) probs[(size_t)r * V_ + idx] = v[j] * inv;
    }
}

extern "C" void kernel_launch(void* const* d_in, const int* in_sizes, int n_in,
                              void* d_out, int out_size, void* d_ws, size_t ws_size,
                              hipStream_t stream) {
    const int*   tv       = (const int*)d_in[0];     // [T,B]
    const float* h0       = (const float*)d_in[1];   // [1,B,H]
    const float* c0       = (const float*)d_in[2];
    const float* enc_raw  = (const float*)d_in[3];   // [S,B,H]
    const int*   lens     = (const int*)d_in[4];     // [B]
    const float* emb      = (const float*)d_in[5];   // [V,E]
    const float* W_ih     = (const float*)d_in[6];   // [4H,E]
    const float* W_hh     = (const float*)d_in[7];   // [4H,H]
    const float* b_ih     = (const float*)d_in[8];
    const float* b_hh     = (const float*)d_in[9];
    const float* We       = (const float*)d_in[10];  // [H,H]
    const float* be       = (const float*)d_in[11];
    const float* Wd       = (const float*)d_in[12];
    const float* bd       = (const float*)d_in[13];
    const float* wa       = (const float*)d_in[14];  // [H]
    const float* ba       = (const float*)d_in[15];  // [1]
    const float* W_out    = (const float*)d_in[16];  // [V,2H]
    const float* b_out    = (const float*)d_in[17];

    // workspace layout (fp32 words; 14.6 MB total)
    float* ws       = (float*)d_ws;
    float* enct     = ws;                       // [S*B,256]   2,097,152
    float* xproj    = ws + 2097152;             // [T*B,1024]    524,288
    float* dect     = ws + 2621440;             // [T*B,256]     131,072
    float* logits   = ws + 2752512;             // [T*B,1000]    512,000
    float* combined = ws + 3264512;             // [T*B,512]     262,144
    u16*   Wt       = (u16*)(ws + 3526656);     // [256,1024] bf16 = 262,144 u16

    // d_out layout (fp32): probs [T,B,V], hT [1,B,H], cT [1,B,H], ctx [B,T,H]
    float* out      = (float*)d_out;
    float* probs    = out;
    float* hT       = out + 512000;
    float* cT       = out + 520192;
    float* ctx_out  = out + 528384;

    // 0) transpose W_hh -> Wt (bf16, [k][r])
    transpose_whh<<<1024, 256, 0, stream>>>(W_hh, Wt);
    // 1) x_proj = gather(emb, tv) @ W_ih^T + b_ih  -> [T*B, 1024]
    {
        dim3 grid(1024 / 64, 512 / 64);
        gemm_bt<<<grid, 256, 0, stream>>>(emb, tv, E_, W_ih, b_ih, xproj, 1024, E_, 1024);
    }
    // 2) enc_t = enc_raw @ We^T + be  -> [S*B, 256]
    {
        dim3 grid(256 / 64, 8192 / 64);
        gemm_bt<<<grid, 256, 0, stream>>>(enc_raw, nullptr, H_, We, be, enct, 256, H_, 256);
    }
    // 3) LSTM scan v6 (32 blocks, u32 W loads, acc[2], unroll-capped)
    lstm_scan6<<<32, 1024, 0, stream>>>(xproj, Wt, b_hh, h0, c0, combined, hT, cT);
    // 4) dec_t = output @ Wd^T + bd  -> [T*B, 256]
    {
        dim3 grid(256 / 64, 512 / 64);
        gemm_bt<<<grid, 256, 0, stream>>>(combined + 256, nullptr, 512, Wd, bd, dect, 256, H_, 256);
    }
    // 5) fused attention -> context
    attn_fused<<<512, 256, 0, stream>>>(enct, dect, enc_raw, wa, ba, lens, ctx_out, combined);
    // 6) logits = combined @ W_out^T + b_out -> [T*B, 1000]
    {
        dim3 grid((1000 + 63) / 64, 512 / 64);
        gemm_bt<<<grid, 256, 0, stream>>>(combined, nullptr, 512, W_out, b_out, logits, V_, 512, V_);
    }
    // 7) vocab softmax -> probs
    vocab_softmax<<<512, 256, 0, stream>>>(logits, probs);
}

// Round 9
// 315.901 us; speedup vs baseline: 1.8911x; 1.0662x over previous
//
#include <hip/hip_runtime.h>
#include <math.h>

typedef unsigned int u32;
typedef unsigned short u16;

#define T_ 16
#define B_ 32
#define S_ 256
#define H_ 256
#define E_ 300
#define V_ 1000

__device__ __forceinline__ float fast_tanh(float x) {
    return 1.0f - 2.0f / (__expf(2.0f * x) + 1.0f);
}
__device__ __forceinline__ float fast_sigm(float x) {
    return 1.0f / (1.0f + __expf(-x));
}
__device__ __forceinline__ float bf2f(u16 x) { return __uint_as_float(((u32)x) << 16); }
__device__ __forceinline__ float blo(u32 u) { return __uint_as_float(u << 16); }
__device__ __forceinline__ float bhi(u32 u) { return __uint_as_float(u & 0xffff0000u); }
__device__ __forceinline__ u16 f2bf(float f) {
    u32 u = __float_as_uint(f);
    u32 r = (u + 0x7fffu + ((u >> 16) & 1u)) >> 16;
    return (u16)r;
}

// ---------------------------------------------------------------------------
// GEMM tile device fn: C[M,N] = A(fp32, opt row-gather) @ Bw[N,K]^T + bias.
// 64x64 tile, BK=32, 256 threads, 4x4/thread. (Proven since round 3.)
// ---------------------------------------------------------------------------
__device__ void gemm_tile_256(const float* __restrict__ A, const int* __restrict__ gidx,
                              int lda, const float* __restrict__ Bw,
                              const float* __restrict__ bias, float* __restrict__ C,
                              int N, int K, int ldc, int bm, int bn)
{
    __shared__ float As[32][64];
    __shared__ float Bs[32][64];
    const int tid = threadIdx.x;
    const int ty = tid >> 4, tx = tid & 15;
    const int lr = tid >> 2;
    const int lk = (tid & 3) * 8;

    int am = bm + lr;
    int arow = gidx ? gidx[am] : am;
    const float* Ap = A + (size_t)arow * lda;
    int bnr = bn + lr;
    const float* Bp = (bnr < N) ? (Bw + (size_t)bnr * K) : nullptr;

    float acc[4][4] = {};

    for (int k0 = 0; k0 < K; k0 += 32) {
        int kb = k0 + lk;
        float av[8];
        if (kb + 8 <= K) {
            float4 p0 = *(const float4*)(Ap + kb);
            float4 p1 = *(const float4*)(Ap + kb + 4);
            av[0]=p0.x; av[1]=p0.y; av[2]=p0.z; av[3]=p0.w;
            av[4]=p1.x; av[5]=p1.y; av[6]=p1.z; av[7]=p1.w;
        } else {
            #pragma unroll
            for (int j = 0; j < 8; j++) av[j] = (kb + j < K) ? Ap[kb + j] : 0.0f;
        }
        #pragma unroll
        for (int j = 0; j < 8; j++) As[lk + j][lr] = av[j];
        if (Bp && kb + 8 <= K) {
            float4 p0 = *(const float4*)(Bp + kb);
            float4 p1 = *(const float4*)(Bp + kb + 4);
            av[0]=p0.x; av[1]=p0.y; av[2]=p0.z; av[3]=p0.w;
            av[4]=p1.x; av[5]=p1.y; av[6]=p1.z; av[7]=p1.w;
        } else if (Bp) {
            #pragma unroll
            for (int j = 0; j < 8; j++) av[j] = (kb + j < K) ? Bp[kb + j] : 0.0f;
        } else {
            #pragma unroll
            for (int j = 0; j < 8; j++) av[j] = 0.0f;
        }
        #pragma unroll
        for (int j = 0; j < 8; j++) Bs[lk + j][lr] = av[j];
        __syncthreads();
        #pragma unroll
        for (int kk = 0; kk < 32; kk++) {
            float4 a = *(const float4*)&As[kk][ty * 4];
            float4 b = *(const float4*)&Bs[kk][tx * 4];
            acc[0][0] += a.x*b.x; acc[0][1] += a.x*b.y; acc[0][2] += a.x*b.z; acc[0][3] += a.x*b.w;
            acc[1][0] += a.y*b.x; acc[1][1] += a.y*b.y; acc[1][2] += a.y*b.z; acc[1][3] += a.y*b.w;
            acc[2][0] += a.z*b.x; acc[2][1] += a.z*b.y; acc[2][2] += a.z*b.z; acc[2][3] += a.z*b.w;
            acc[3][0] += a.w*b.x; acc[3][1] += a.w*b.y; acc[3][2] += a.w*b.z; acc[3][3] += a.w*b.w;
        }
        __syncthreads();
    }
    #pragma unroll
    for (int i = 0; i < 4; i++) {
        int m = bm + ty * 4 + i;
        #pragma unroll
        for (int j = 0; j < 4; j++) {
            int n = bn + tx * 4 + j;
            if (n < N) C[(size_t)m * ldc + n] = acc[i][j] + bias[n];
        }
    }
}

// ---------------------------------------------------------------------------
// Kernel 1: heterogeneous prep — xproj GEMM tiles + Whh transpose(bf16) +
// Wd transpose(fp32). 256 threads/block.
//   bid <  128          : xproj tile (M=512, N=1024, K=300, gather emb by tv)
//   128 <= bid < 1152   : Wt[k*1024+r] = bf16(Whh[r*256+k])
//   1152 <= bid < 1408  : Wdt[k*256+h] = Wd[h*256+k]
// ---------------------------------------------------------------------------
__global__ __launch_bounds__(256)
void prep_xproj(const float* __restrict__ emb, const int* __restrict__ tv,
                const float* __restrict__ W_ih, const float* __restrict__ b_ih,
                float* __restrict__ xproj,
                const float* __restrict__ Whh, u16* __restrict__ Wt,
                const float* __restrict__ Wd, float* __restrict__ Wdt)
{
    const int bid = blockIdx.x;
    if (bid < 128) {
        gemm_tile_256(emb, tv, E_, W_ih, b_ih, xproj, 1024, E_, 1024,
                      (bid >> 4) * 64, (bid & 15) * 64);
    } else if (bid < 1152) {
        int idx = (bid - 128) * 256 + threadIdx.x;   // 0..262143
        int k = idx >> 10;
        int r = idx & 1023;
        Wt[idx] = f2bf(Whh[(size_t)r * 256 + k]);
    } else {
        int idx = (bid - 1152) * 256 + threadIdx.x;  // 0..65535
        int k = idx >> 8;
        int h = idx & 255;
        Wdt[idx] = Wd[(size_t)h * 256 + k];
    }
}

// ---------------------------------------------------------------------------
// Kernel 2: heterogeneous lstm + enc_t. 1024 threads/block, grid = 32+128.
//   bid < 32 : LSTM scan (round-8 proven v6 inner loop: u32 W loads, acc[2],
//              unroll-2 cap — keeps VGPR ~28, no spill).
//   bid >= 32: enc_t 128x128 tile (M=8192, N=256, K=256) on otherwise-idle
//              CUs, hidden under the lstm's 16-step critical path.
// ---------------------------------------------------------------------------
__global__ __launch_bounds__(1024, 4)
void lstm_enct(const float* __restrict__ xproj,   // [T,B,1024]
               const u16*   __restrict__ Wt,      // [256,1024] bf16
               const float* __restrict__ bhh,     // [1024]
               const float* __restrict__ h0, const float* __restrict__ c0,
               float* __restrict__ combined,      // [T,B,512] second half
               float* __restrict__ hT, float* __restrict__ cT,
               const float* __restrict__ enc_raw, // [S,B,H] = [8192,256]
               const float* __restrict__ We,      // [256,256]
               const float* __restrict__ be,
               float* __restrict__ enct)          // [8192,256]
{
    const int bid = blockIdx.x;
    const int tid = threadIdx.x;
    __shared__ float hs[256], cs[256];
    __shared__ float zp[2][1024];
    __shared__ float As2[32][132];   // +4 pad: breaks 8-way write conflict
    __shared__ float Bs2[32][132];

    if (bid < 32) {
        // ----- LSTM path -----
        const int b  = bid;
        const int kg = tid >> 9;          // 0..1
        const int rq = tid & 511;
        const int r0 = rq * 2;
        if (tid < 256) {
            hs[tid] = h0[b * 256 + tid];
            cs[tid] = c0[b * 256 + tid];
        }
        const float bh = bhh[tid];
        const u16* wbase = Wt + (size_t)(kg * 128) * 1024 + r0;
        __syncthreads();

        for (int t = 0; t < T_; t++) {
            float a0 = 0.f, a1 = 0.f;
            #pragma unroll 2
            for (int kk = 0; kk < 128; kk += 4) {
                float4 h4 = *(const float4*)&hs[kg * 128 + kk];
                u32 w0 = *(const u32*)(wbase + (size_t)(kk + 0) * 1024);
                u32 w1 = *(const u32*)(wbase + (size_t)(kk + 1) * 1024);
                u32 w2 = *(const u32*)(wbase + (size_t)(kk + 2) * 1024);
                u32 w3 = *(const u32*)(wbase + (size_t)(kk + 3) * 1024);
                a0 += blo(w0)*h4.x; a1 += bhi(w0)*h4.x;
                a0 += blo(w1)*h4.y; a1 += bhi(w1)*h4.y;
                a0 += blo(w2)*h4.z; a1 += bhi(w2)*h4.z;
                a0 += blo(w3)*h4.w; a1 += bhi(w3)*h4.w;
            }
            *(float2*)&zp[kg][r0] = make_float2(a0, a1);
            __syncthreads();

            float z = xproj[((size_t)t * B_ + b) * 1024 + tid] + bh
                    + zp[0][tid] + zp[1][tid];
            __syncthreads();
            zp[0][tid] = z;
            __syncthreads();

            if (tid < 256) {
                float ig = fast_sigm(zp[0][tid]);
                float fg = fast_sigm(zp[0][256 + tid]);
                float gg = fast_tanh(zp[0][512 + tid]);
                float og = fast_sigm(zp[0][768 + tid]);
                float c = fg * cs[tid] + ig * gg;
                float h = og * fast_tanh(c);
                cs[tid] = c;
                hs[tid] = h;
                combined[((size_t)t * B_ + b) * 512 + 256 + tid] = h;
                if (t == T_ - 1) {
                    hT[b * 256 + tid] = h;
                    cT[b * 256 + tid] = c;
                }
            }
            __syncthreads();
        }
    } else {
        // ----- enc_t path: 128x128 tile, 1024 threads, 4x4 per thread -----
        const int tile = bid - 32;
        const int bm = (tile >> 1) * 128;
        const int bn = (tile & 1) * 128;
        const int tx = tid & 31, ty = tid >> 5;   // 32x32 threads
        const int lr = tid >> 3;                  // 0..127
        const int lk = (tid & 7) * 4;             // 0,4,..,28

        const float* Ap = enc_raw + (size_t)(bm + lr) * 256;
        const float* Bp = We + (size_t)(bn + lr) * 256;
        float acc[4][4] = {};

        for (int k0 = 0; k0 < 256; k0 += 32) {
            float4 a4 = *(const float4*)(Ap + k0 + lk);
            float4 b4 = *(const float4*)(Bp + k0 + lk);
            As2[lk + 0][lr] = a4.x; As2[lk + 1][lr] = a4.y;
            As2[lk + 2][lr] = a4.z; As2[lk + 3][lr] = a4.w;
            Bs2[lk + 0][lr] = b4.x; Bs2[lk + 1][lr] = b4.y;
            Bs2[lk + 2][lr] = b4.z; Bs2[lk + 3][lr] = b4.w;
            __syncthreads();
            #pragma unroll
            for (int kk = 0; kk < 32; kk++) {
                float4 a = *(const float4*)&As2[kk][ty * 4];
                float4 b = *(const float4*)&Bs2[kk][tx * 4];
                acc[0][0] += a.x*b.x; acc[0][1] += a.x*b.y; acc[0][2] += a.x*b.z; acc[0][3] += a.x*b.w;
                acc[1][0] += a.y*b.x; acc[1][1] += a.y*b.y; acc[1][2] += a.y*b.z; acc[1][3] += a.y*b.w;
                acc[2][0] += a.z*b.x; acc[2][1] += a.z*b.y; acc[2][2] += a.z*b.z; acc[2][3] += a.z*b.w;
                acc[3][0] += a.w*b.x; acc[3][1] += a.w*b.y; acc[3][2] += a.w*b.z; acc[3][3] += a.w*b.w;
            }
            __syncthreads();
        }
        #pragma unroll
        for (int i = 0; i < 4; i++) {
            int m = bm + ty * 4 + i;
            #pragma unroll
            for (int j = 0; j < 4; j++) {
                int n = bn + tx * 4 + j;
                enct[(size_t)m * 256 + n] = acc[i][j] + be[n];
            }
        }
    }
}

// ---------------------------------------------------------------------------
// Kernel 3: attention with inlined dec_t row. Block per (b,t), 256 threads.
// dec_t[h] = bd[h] + sum_k Wdt[k][h]*out[k]  (Wdt k-major -> coalesced lanes)
// ---------------------------------------------------------------------------
__global__ __launch_bounds__(256)
void attn2(const float* __restrict__ enct,     // [S,B,H]
           const float* __restrict__ combined_in, // [T,B,512] (2nd half = out)
           const float* __restrict__ Wdt,      // [256,256] k-major
           const float* __restrict__ bd,
           const float* __restrict__ enc_raw,  // [S,B,H]
           const float* __restrict__ wa, const float* __restrict__ ba,
           const int* __restrict__ lens,
           float* __restrict__ ctx_out,        // [B,T,H] (d_out)
           float* __restrict__ combined_out)   // [T,B,512] first half
{
    const int bid = blockIdx.x;
    const int b = bid >> 4;
    const int t = bid & 15;
    const int tid = threadIdx.x;
    __shared__ float outs[256], ds[256], was[256], sc[256];
    __shared__ float red[8];

    outs[tid] = combined_in[((size_t)t * B_ + b) * 512 + 256 + tid];
    was[tid]  = wa[tid];
    const int len = lens[b];
    const float bav = ba[0];
    __syncthreads();

    // dec_t row for this (t,b)
    {
        float acc = bd[tid];
        const float* wp = Wdt + tid;
        #pragma unroll 4
        for (int k = 0; k < 256; k++) acc += wp[(size_t)k * 256] * outs[k];
        ds[tid] = acc;
    }
    __syncthreads();

    const int wv = tid >> 6, lane = tid & 63;
    for (int s = wv; s < len; s += 4) {
        const float* er = enct + ((size_t)s * B_ + b) * 256;
        float sum = 0.0f;
        #pragma unroll
        for (int j = 0; j < 4; j++) {
            int h = lane + 64 * j;
            sum += fast_tanh(er[h] + ds[h]) * was[h];
        }
        #pragma unroll
        for (int off = 32; off >= 1; off >>= 1) sum += __shfl_xor(sum, off, 64);
        if (lane == 0) sc[s] = sum + bav;
    }
    __syncthreads();

    float x = (tid < len) ? sc[tid] : -INFINITY;
    float m = x;
    #pragma unroll
    for (int off = 32; off >= 1; off >>= 1) m = fmaxf(m, __shfl_xor(m, off, 64));
    if (lane == 0) red[wv] = m;
    __syncthreads();
    m = fmaxf(fmaxf(red[0], red[1]), fmaxf(red[2], red[3]));
    float e = __expf(x - m);
    float ssum = e;
    #pragma unroll
    for (int off = 32; off >= 1; off >>= 1) ssum += __shfl_xor(ssum, off, 64);
    if (lane == 0) red[4 + wv] = ssum;
    __syncthreads();
    ssum = red[4] + red[5] + red[6] + red[7];
    __syncthreads();
    sc[tid] = e / ssum;
    __syncthreads();

    float acc = 0.0f;
    const float* eb = enc_raw + (size_t)b * 256 + tid;
    for (int s = 0; s < len; s++) acc += sc[s] * eb[(size_t)s * (B_ * H_)];
    ctx_out[((size_t)b * T_ + t) * 256 + tid] = acc;
    combined_out[((size_t)t * B_ + b) * 512 + tid] = acc;
}

// ---------------------------------------------------------------------------
// Kernel 4: logits GEMM (standalone 64x64 tiles).
// ---------------------------------------------------------------------------
__global__ __launch_bounds__(256)
void gemm_logits(const float* __restrict__ A, const float* __restrict__ Bw,
                 const float* __restrict__ bias, float* __restrict__ C)
{
    gemm_tile_256(A, nullptr, 512, Bw, bias, C, V_, 512, V_,
                  blockIdx.y * 64, blockIdx.x * 64);
}

// ---------------------------------------------------------------------------
// Kernel 5: vocab softmax. Block per (t,b) row, 256 threads x 4 (V=1000).
// ---------------------------------------------------------------------------
__global__ __launch_bounds__(256)
void vocab_softmax(const float* __restrict__ logits, float* __restrict__ probs)
{
    const int r = blockIdx.x;
    const int tid = threadIdx.x;
    const int wv = tid >> 6, lane = tid & 63;
    __shared__ float red[8];
    const float* row = logits + (size_t)r * V_;
    float v[4];
    float mx = -INFINITY;
    #pragma unroll
    for (int j = 0; j < 4; j++) {
        int idx = tid + 256 * j;
        v[j] = (idx < V_) ? row[idx] : -INFINITY;
        mx = fmaxf(mx, v[j]);
    }
    #pragma unroll
    for (int off = 32; off >= 1; off >>= 1) mx = fmaxf(mx, __shfl_xor(mx, off, 64));
    if (lane == 0) red[wv] = mx;
    __syncthreads();
    mx = fmaxf(fmaxf(red[0], red[1]), fmaxf(red[2], red[3]));
    float s = 0.0f;
    #pragma unroll
    for (int j = 0; j < 4; j++) {
        v[j] = __expf(v[j] - mx);
        s += v[j];
    }
    #pragma unroll
    for (int off = 32; off >= 1; off >>= 1) s += __shfl_xor(s, off, 64);
    if (lane == 0) red[4 + wv] = s;
    __syncthreads();
    s = red[4] + red[5] + red[6] + red[7];
    float inv = 1.0f / s;
    #pragma unroll
    for (int j = 0; j < 4; j++) {
        int idx = tid + 256 * j;
        if (idx < V_) probs[(size_t)r * V_ + idx] = v[j] * inv;
    }
}

extern "C" void kernel_launch(void* const* d_in, const int* in_sizes, int n_in,
                              void* d_out, int out_size, void* d_ws, size_t ws_size,
                              hipStream_t stream) {
    const int*   tv       = (const int*)d_in[0];     // [T,B]
    const float* h0       = (const float*)d_in[1];   // [1,B,H]
    const float* c0       = (const float*)d_in[2];
    const float* enc_raw  = (const float*)d_in[3];   // [S,B,H]
    const int*   lens     = (const int*)d_in[4];     // [B]
    const float* emb      = (const float*)d_in[5];   // [V,E]
    const float* W_ih     = (const float*)d_in[6];   // [4H,E]
    const float* W_hh     = (const float*)d_in[7];   // [4H,H]
    const float* b_ih     = (const float*)d_in[8];
    const float* b_hh     = (const float*)d_in[9];
    const float* We       = (const float*)d_in[10];  // [H,H]
    const float* be       = (const float*)d_in[11];
    const float* Wd       = (const float*)d_in[12];
    const float* bd       = (const float*)d_in[13];
    const float* wa       = (const float*)d_in[14];  // [H]
    const float* ba       = (const float*)d_in[15];  // [1]
    const float* W_out    = (const float*)d_in[16];  // [V,2H]
    const float* b_out    = (const float*)d_in[17];

    // workspace layout (fp32 words; same proven 14.63 MB footprint)
    float* ws       = (float*)d_ws;
    float* enct     = ws;                       // [S*B,256]   2,097,152
    float* xproj    = ws + 2097152;             // [T*B,1024]    524,288
    float* Wdt      = ws + 2621440;             // [256,256]      65,536 (old dect slot)
    float* logits   = ws + 2752512;             // [T*B,1000]    512,000
    float* combined = ws + 3264512;             // [T*B,512]     262,144
    u16*   Wt       = (u16*)(ws + 3526656);     // [256,1024] bf16

    // d_out layout (fp32): probs [T,B,V], hT [1,B,H], cT [1,B,H], ctx [B,T,H]
    float* out      = (float*)d_out;
    float* probs    = out;
    float* hT       = out + 512000;
    float* cT       = out + 520192;
    float* ctx_out  = out + 528384;

    // 1) xproj GEMM + Whh/Wd transposes (heterogeneous grid)
    prep_xproj<<<1408, 256, 0, stream>>>(emb, tv, W_ih, b_ih, xproj, W_hh, Wt, Wd, Wdt);
    // 2) LSTM (blocks 0-31) + enc_t GEMM (blocks 32-159) concurrently
    lstm_enct<<<160, 1024, 0, stream>>>(xproj, Wt, b_hh, h0, c0, combined, hT, cT,
                                        enc_raw, We, be, enct);
    // 3) attention with inlined dec_t
    attn2<<<512, 256, 0, stream>>>(enct, combined, Wdt, bd, enc_raw, wa, ba, lens,
                                   ctx_out, combined);
    // 4) logits = combined @ W_out^T + b_out
    {
        dim3 grid((1000 + 63) / 64, 512 / 64);
        gemm_logits<<<grid, 256, 0, stream>>>(combined, W_out, b_out, logits);
    }
    // 5) vocab softmax
    vocab_softmax<<<512, 256, 0, stream>>>(logits, probs);
}